// Round 3
// baseline (31120.016 us; speedup 1.0000x reference)
//
#include <hip/hip_runtime.h>
#include <math.h>

#define VOCAB 32000
#define EMBD  512
#define HID   1024
#define BATCH 32
#define SEQ   64
#define TENC  64
#define NSTEP 63          // S-1 decode steps
#define G4    (4*HID)

struct GP {
  const float* A;     // MODE0: plain A, row stride K
  const float* segA;  // MODE1: attn_h ; MODE2: first 1024-seg
  const float* segB;  // MODE1: h0     ; MODE2: second 1024-seg
  const float* emb;   // MODE1
  const int*   tgt;   // MODE1: (B,S) row-major
  int t;
  const float* W1;    // row-major [N, ws1]
  const float* W2;    // row-major [N, ws2]
  int ws1, ws2;
  const float* b1;
  const float* b2;
  float* C;
  int ldc;
  int K;
  int act;            // 0 none, 1 tanh
};

__device__ __forceinline__ float4 ldg4(const float* p) {
  return *reinterpret_cast<const float4*>(p);
}

// C[32 x N] = A[32 x K] * W[N x K]^T (+bias)(+tanh). NT=32 per block, 2x2/thread.
// MODE 0: plain A. MODE 1: A=[emb(tok)|attn_h|h0], W=[Wih0|Whh0].
// MODE 2: A=[segA|segB] (1024 each), W=[W1|W2].
template<int MODE>
__global__ __launch_bounds__(256) void gemm32(GP P) {
  __shared__ float At[32][34];
  __shared__ float Wt[32][34];
  const int j  = threadIdx.x;
  const int n0 = blockIdx.x * 32;
  const int m0 = blockIdx.y * 32;
  const int lr = j >> 3;          // 0..31 tile row
  const int lc = (j & 7) << 2;    // 0,4,..,28 k within tile
  const int tn = j & 15;
  const int tm = j >> 4;          // 0..15
  float a00=0.f, a01=0.f, a10=0.f, a11=0.f;
  for (int k0 = 0; k0 < P.K; k0 += 32) {
    const int k = k0 + lc;
    float4 av, wv;
    if (MODE == 0) {
      av = ldg4(P.A + (size_t)(m0 + lr) * P.K + k);
    } else if (MODE == 1) {
      if (k < EMBD) {
        const int tok = P.tgt[lr * SEQ + P.t];
        av = ldg4(P.emb + (size_t)tok * EMBD + k);
      } else if (k < EMBD + HID) {
        av = ldg4(P.segA + lr * HID + (k - EMBD));
      } else {
        av = ldg4(P.segB + lr * HID + (k - EMBD - HID));
      }
    } else {
      if (k < HID) av = ldg4(P.segA + lr * HID + k);
      else         av = ldg4(P.segB + lr * HID + (k - HID));
    }
    {
      const int n = n0 + lr;
      if (MODE == 1) {
        if (k < EMBD + HID) wv = ldg4(P.W1 + (size_t)n * (EMBD + HID) + k);
        else                wv = ldg4(P.W2 + (size_t)n * HID + (k - EMBD - HID));
      } else if (MODE == 2) {
        if (k < HID) wv = ldg4(P.W1 + (size_t)n * P.ws1 + k);
        else         wv = ldg4(P.W2 + (size_t)n * P.ws2 + (k - HID));
      } else {
        wv = ldg4(P.W1 + (size_t)n * P.ws1 + k);
      }
    }
    __syncthreads();
    At[lc+0][lr]=av.x; At[lc+1][lr]=av.y; At[lc+2][lr]=av.z; At[lc+3][lr]=av.w;
    Wt[lc+0][lr]=wv.x; Wt[lc+1][lr]=wv.y; Wt[lc+2][lr]=wv.z; Wt[lc+3][lr]=wv.w;
    __syncthreads();
    #pragma unroll
    for (int kk = 0; kk < 32; ++kk) {
      const float2 a = *reinterpret_cast<const float2*>(&At[kk][tm*2]);
      const float2 w = *reinterpret_cast<const float2*>(&Wt[kk][tn*2]);
      a00 += a.x*w.x; a01 += a.x*w.y; a10 += a.y*w.x; a11 += a.y*w.y;
    }
  }
  const int na = n0 + tn*2, ma = m0 + tm*2;
  float b0 = 0.f, b1v = 0.f;
  if (P.b1) { b0  = P.b1[na]; b1v  = P.b1[na+1]; }
  if (P.b2) { b0 += P.b2[na]; b1v += P.b2[na+1]; }
  float c00=a00+b0, c01=a01+b1v, c10=a10+b0, c11=a11+b1v;
  if (P.act) { c00=tanhf(c00); c01=tanhf(c01); c10=tanhf(c10); c11=tanhf(c11); }
  P.C[(size_t)ma     * P.ldc + na  ] = c00;
  P.C[(size_t)ma     * P.ldc + na+1] = c01;
  P.C[(size_t)(ma+1) * P.ldc + na  ] = c10;
  P.C[(size_t)(ma+1) * P.ldc + na+1] = c11;
}

// Wide-N plain GEMM: C[M x N] = A*W^T + bias. NT=128/block, 4x4 per thread.
__global__ __launch_bounds__(256) void gemm128(GP P) {
  __shared__ float At[32][36];
  __shared__ float Wt[32][132];
  const int j  = threadIdx.x;
  const int n0 = blockIdx.x * 128;
  const int m0 = blockIdx.y * 32;
  const int lr = j >> 3;
  const int lc = (j & 7) << 2;
  const int tn = j & 31;
  const int tm = j >> 5;          // 0..7
  float acc[4][4];
  #pragma unroll
  for (int i=0;i<4;++i) {
    acc[i][0]=0.f; acc[i][1]=0.f; acc[i][2]=0.f; acc[i][3]=0.f;
  }
  for (int k0 = 0; k0 < P.K; k0 += 32) {
    const int k = k0 + lc;
    float4 av = ldg4(P.A + (size_t)(m0+lr)*P.K + k);
    float4 wv[4];
    #pragma unroll
    for (int rep = 0; rep < 4; ++rep) {
      const int n = n0 + lr + rep*32;
      wv[rep] = ldg4(P.W1 + (size_t)n * P.ws1 + k);
    }
    __syncthreads();
    At[lc+0][lr]=av.x; At[lc+1][lr]=av.y; At[lc+2][lr]=av.z; At[lc+3][lr]=av.w;
    #pragma unroll
    for (int rep=0; rep<4; ++rep) {
      const int r = lr + rep*32;
      Wt[lc+0][r]=wv[rep].x; Wt[lc+1][r]=wv[rep].y; Wt[lc+2][r]=wv[rep].z; Wt[lc+3][r]=wv[rep].w;
    }
    __syncthreads();
    #pragma unroll
    for (int kk=0; kk<32; ++kk) {
      const float4 a = *reinterpret_cast<const float4*>(&At[kk][tm*4]);
      const float4 w = *reinterpret_cast<const float4*>(&Wt[kk][tn*4]);
      acc[0][0]+=a.x*w.x; acc[0][1]+=a.x*w.y; acc[0][2]+=a.x*w.z; acc[0][3]+=a.x*w.w;
      acc[1][0]+=a.y*w.x; acc[1][1]+=a.y*w.y; acc[1][2]+=a.y*w.z; acc[1][3]+=a.y*w.w;
      acc[2][0]+=a.z*w.x; acc[2][1]+=a.z*w.y; acc[2][2]+=a.z*w.z; acc[2][3]+=a.z*w.w;
      acc[3][0]+=a.w*w.x; acc[3][1]+=a.w*w.y; acc[3][2]+=a.w*w.z; acc[3][3]+=a.w*w.w;
    }
  }
  const int na = n0 + tn*4, ma = m0 + tm*4;
  float bb[4] = {0.f,0.f,0.f,0.f};
  if (P.b1) { bb[0]=P.b1[na]; bb[1]=P.b1[na+1]; bb[2]=P.b1[na+2]; bb[3]=P.b1[na+3]; }
  #pragma unroll
  for (int i=0;i<4;++i) {
    #pragma unroll
    for (int x=0;x<4;++x) {
      float c = acc[i][x] + bb[x];
      if (P.act) c = tanhf(c);
      P.C[(size_t)(ma+i)*P.ldc + na+x] = c;
    }
  }
}

__global__ __launch_bounds__(256) void lstm_cell_k(const float* __restrict__ g,
                                                   float* __restrict__ h,
                                                   float* __restrict__ c) {
  const int i = blockIdx.x*256 + threadIdx.x;   // [0, B*H)
  const int b = i / HID, n = i % HID;
  const float* gb = g + (size_t)b*G4;
  const float gi = gb[n], gf = gb[HID+n], gg = gb[2*HID+n], go = gb[3*HID+n];
  const float si = 1.f/(1.f+expf(-gi));
  const float sf = 1.f/(1.f+expf(-gf));
  const float so = 1.f/(1.f+expf(-go));
  const float cn = sf*c[i] + si*tanhf(gg);
  c[i] = cn;
  h[i] = so*tanhf(cn);
}

// per-b block: scores over T, softmax, context
__global__ __launch_bounds__(256) void attn_k(const float* __restrict__ q,
                                              const float* __restrict__ Pre,
                                              const float* __restrict__ va,
                                              const float* __restrict__ enc,
                                              float* __restrict__ context) {
  const int b = blockIdx.x;
  const int tid = threadIdx.x;
  const int lane = tid & 63, wid = tid >> 6;   // 4 waves
  __shared__ float sw[TENC];
  __shared__ float swx[TENC];
  const float* qb = q + (size_t)b*HID;
  float qreg[16], vreg[16];
  #pragma unroll
  for (int i=0;i<16;++i) { qreg[i] = qb[lane + 64*i]; vreg[i] = va[lane + 64*i]; }
  for (int t = wid; t < TENC; t += 4) {
    const float* pr = Pre + ((size_t)t*BATCH + b)*HID;
    float s = 0.f;
    #pragma unroll
    for (int i=0;i<16;++i) s += vreg[i]*tanhf(qreg[i] + pr[lane + 64*i]);
    for (int off = 32; off > 0; off >>= 1) s += __shfl_xor(s, off);
    if (lane == 0) sw[t] = s;
  }
  __syncthreads();
  if (wid == 0) {                       // softmax over T=64 on one wave
    float v = sw[lane];
    float mx = v;
    for (int off=32; off>0; off>>=1) mx = fmaxf(mx, __shfl_xor(mx, off));
    const float e = expf(v - mx);
    float sum = e;
    for (int off=32; off>0; off>>=1) sum += __shfl_xor(sum, off);
    swx[lane] = e / sum;
  }
  __syncthreads();
  for (int h = tid; h < HID; h += 256) {
    float s = 0.f;
    for (int t = 0; t < TENC; ++t) s += swx[t] * enc[((size_t)t*BATCH + b)*HID + h];
    context[(size_t)b*HID + h] = s;
  }
}

// per-(b,t) block: in-place logits -> log-softmax, + argmax word (as float)
__global__ __launch_bounds__(256) void lsm_k(float* __restrict__ out,
                                             float* __restrict__ words) {
  const int b = blockIdx.x;
  const int t = blockIdx.y;
  float* row = out + ((size_t)t*BATCH + b)*VOCAB;
  const int tid = threadIdx.x;
  float m = -INFINITY; int mi = 0;
  for (int v = tid; v < VOCAB; v += 256) {
    const float x = row[v];
    if (x > m) { m = x; mi = v; }
  }
  __shared__ float sm[256]; __shared__ int si[256];
  sm[tid] = m; si[tid] = mi;
  __syncthreads();
  for (int s2 = 128; s2; s2 >>= 1) {
    if (tid < s2) {
      const float om = sm[tid+s2]; const int oi = si[tid+s2];
      if (om > sm[tid] || (om == sm[tid] && oi < si[tid])) { sm[tid]=om; si[tid]=oi; }
    }
    __syncthreads();
  }
  const float mx = sm[0]; const int amax = si[0];
  float s = 0.f;
  for (int v = tid; v < VOCAB; v += 256) s += expf(row[v]-mx);
  __shared__ float ss[256];
  ss[tid] = s; __syncthreads();
  for (int s2=128; s2; s2>>=1) { if (tid < s2) ss[tid] += ss[tid+s2]; __syncthreads(); }
  const float lse = logf(ss[0]) + mx;
  for (int v = tid; v < VOCAB; v += 256) row[v] = row[v] - lse;
  if (tid == 0) words[(size_t)t*BATCH + b] = (float)amax;
}

__global__ __launch_bounds__(256) void init_k(const float* __restrict__ enc_h,
                                              const float* __restrict__ enc_c,
                                              float* h0, float* h1, float* c0,
                                              float* c1, float* ah) {
  const int i = blockIdx.x*256 + threadIdx.x;
  if (i < BATCH*HID) {
    h0[i] = enc_h[i]; h1[i] = enc_h[BATCH*HID + i];
    c0[i] = enc_c[i]; c1[i] = enc_c[BATCH*HID + i];
    ah[i] = 0.f;
  }
}

extern "C" void kernel_launch(void* const* d_in, const int* in_sizes, int n_in,
                              void* d_out, int out_size, void* d_ws, size_t ws_size,
                              hipStream_t stream) {
  const int*   tgt   = (const int*)d_in[0];
  const float* enc_h = (const float*)d_in[1];
  const float* enc_c = (const float*)d_in[2];
  const float* enc   = (const float*)d_in[3];
  const float* emb   = (const float*)d_in[4];
  const float* Wih0  = (const float*)d_in[5];
  const float* Whh0  = (const float*)d_in[6];
  const float* bih0  = (const float*)d_in[7];
  const float* bhh0  = (const float*)d_in[8];
  const float* Wih1  = (const float*)d_in[9];
  const float* Whh1  = (const float*)d_in[10];
  const float* bih1  = (const float*)d_in[11];
  const float* bhh1  = (const float*)d_in[12];
  const float* Wa    = (const float*)d_in[13];
  const float* ba    = (const float*)d_in[14];
  const float* va    = (const float*)d_in[15];
  const float* Wc    = (const float*)d_in[16];
  const float* bc    = (const float*)d_in[17];
  const float* Wo    = (const float*)d_in[18];
  const float* bo    = (const float*)d_in[19];

  float* ws  = (float*)d_ws;
  float* Pre = ws;                           // [T*B, H] = 2M floats
  float* gbf = Pre + (size_t)TENC*BATCH*HID; // [B, 4H]
  float* h0  = gbf + (size_t)BATCH*G4;
  float* c0  = h0 + BATCH*HID;
  float* h1v = c0 + BATCH*HID;
  float* c1v = h1v + BATCH*HID;
  float* ah  = c1v + BATCH*HID;
  float* qv  = ah + BATCH*HID;
  float* ctx = qv + BATCH*HID;

  float* out   = (float*)d_out;
  float* words = out + (size_t)NSTEP*BATCH*VOCAB;

  init_k<<<dim3((BATCH*HID+255)/256), 256, 0, stream>>>(enc_h, enc_c, h0, h1v, c0, c1v, ah);

  { // Pre = enc @ Wa2^T + ba   (time-invariant attention term)
    GP p = {};
    p.A = enc; p.W1 = Wa + HID; p.ws1 = 2*HID; p.b1 = ba;
    p.C = Pre; p.ldc = HID; p.K = HID; p.act = 0;
    gemm128<<<dim3(HID/128, (TENC*BATCH)/32), 256, 0, stream>>>(p);
  }

  for (int t = 0; t < NSTEP; ++t) {
    { // gates0 = [emb|attn_h|h0] @ [Wih0|Whh0]^T + biases
      GP p = {};
      p.emb = emb; p.tgt = tgt; p.t = t; p.segA = ah; p.segB = h0;
      p.W1 = Wih0; p.W2 = Whh0; p.ws1 = EMBD+HID; p.ws2 = HID;
      p.b1 = bih0; p.b2 = bhh0; p.C = gbf; p.ldc = G4; p.K = EMBD + 2*HID; p.act = 0;
      gemm32<1><<<dim3(G4/32, 1), 256, 0, stream>>>(p);
    }
    lstm_cell_k<<<dim3(BATCH*HID/256), 256, 0, stream>>>(gbf, h0, c0);
    { // gates1 = [h0|h1] @ [Wih1|Whh1]^T + biases
      GP p = {};
      p.segA = h0; p.segB = h1v;
      p.W1 = Wih1; p.W2 = Whh1; p.ws1 = HID; p.ws2 = HID;
      p.b1 = bih1; p.b2 = bhh1; p.C = gbf; p.ldc = G4; p.K = 2*HID; p.act = 0;
      gemm32<2><<<dim3(G4/32, 1), 256, 0, stream>>>(p);
    }
    lstm_cell_k<<<dim3(BATCH*HID/256), 256, 0, stream>>>(gbf, h1v, c1v);
    { // q = h1 @ Wa1^T
      GP p = {};
      p.A = h1v; p.W1 = Wa; p.ws1 = 2*HID; p.b1 = nullptr;
      p.C = qv; p.ldc = HID; p.K = HID; p.act = 0;
      gemm32<0><<<dim3(HID/32, 1), 256, 0, stream>>>(p);
    }
    attn_k<<<dim3(BATCH), 256, 0, stream>>>(qv, Pre, va, enc, ctx);
    { // attn_h = tanh([h1|ctx] @ Wc^T + bc)
      GP p = {};
      p.segA = h1v; p.segB = ctx;
      p.W1 = Wc; p.W2 = Wc + HID; p.ws1 = 2*HID; p.ws2 = 2*HID;
      p.b1 = bc; p.b2 = nullptr; p.C = ah; p.ldc = HID; p.K = 2*HID; p.act = 1;
      gemm32<2><<<dim3(HID/32, 1), 256, 0, stream>>>(p);
    }
    { // logits(t) = attn_h @ Wo^T + bo  -> written into out[t]
      GP p = {};
      p.A = ah; p.W1 = Wo; p.ws1 = HID; p.b1 = bo;
      p.C = out + (size_t)t*BATCH*VOCAB; p.ldc = VOCAB; p.K = HID; p.act = 0;
      gemm128<<<dim3(VOCAB/128, 1), 256, 0, stream>>>(p);
    }
  }
  // deferred: log-softmax + argmax for all steps at once (not in recurrence)
  lsm_k<<<dim3(BATCH, NSTEP), 256, 0, stream>>>(out, words);
}

// Round 4
// 13441.391 us; speedup vs baseline: 2.3152x; 2.3152x over previous
//
#include <hip/hip_runtime.h>
#include <math.h>

#define VOCAB 32000
#define EMBD  512
#define HID   1024
#define BATCH 32
#define SEQ   64
#define TENC  64
#define NSTEP 63          // S-1 decode steps
#define G4    4096

__device__ __forceinline__ float4 ldg4(const float* p) {
  return *reinterpret_cast<const float4*>(p);
}

// ---------- K-split partial GEMM: P[sp][32][N] = A[32 x Kchunk] * W[N x Kchunk]^T
// MODE 0 (gates0): A=[emb(tok)|ah|h0] K=2560, W=[Wih0(stride 1536)|Whh0(1024)], chunk=640, splits=4
// MODE 1 (gates1): A=[h0|h1] K=2048, W=[Wih1|Whh1] (stride 1024), chunk=512, splits=4
// MODE 2 (proj):   A=h1 K=1024, W rows j<1024: Wa[j, 0:1024] (stride 2048); else Wc[j-1024, 0:1024], chunk=512, splits=2
struct PP {
  const float* ah; const float* h0; const float* h1;
  const float* emb; const int* tgt; int t;
  const float* WA; const float* WB;
  float* P; int N;
};

template<int MODE>
__global__ __launch_bounds__(256) void pgemm(PP P) {
  __shared__ float At[32][34];
  __shared__ float Wt[32][34];
  const int j  = threadIdx.x;
  const int n0 = blockIdx.x * 32;
  const int sp = blockIdx.y;
  const int CH = (MODE == 0) ? 640 : 512;
  const int kbeg = sp * CH;
  const int lr = j >> 3;          // 0..31
  const int lc = (j & 7) << 2;    // 0,4,..28
  const int tn = j & 15;
  const int tm = j >> 4;          // 0..15
  float a00=0.f, a01=0.f, a10=0.f, a11=0.f;
  for (int k0 = kbeg; k0 < kbeg + CH; k0 += 32) {
    const int k = k0 + lc;
    float4 av, wv;
    if (MODE == 0) {
      if (k < EMBD) {
        const int tok = P.tgt[lr * SEQ + P.t];
        av = ldg4(P.emb + (size_t)tok * EMBD + k);
      } else if (k < EMBD + HID) {
        av = ldg4(P.ah + lr * HID + (k - EMBD));
      } else {
        av = ldg4(P.h0 + lr * HID + (k - EMBD - HID));
      }
      const int n = n0 + lr;
      if (k < EMBD + HID) wv = ldg4(P.WA + (size_t)n * (EMBD + HID) + k);
      else                wv = ldg4(P.WB + (size_t)n * HID + (k - EMBD - HID));
    } else if (MODE == 1) {
      const int n = n0 + lr;
      if (k < HID) { av = ldg4(P.h0 + lr * HID + k);        wv = ldg4(P.WA + (size_t)n * HID + k); }
      else         { av = ldg4(P.h1 + lr * HID + (k - HID)); wv = ldg4(P.WB + (size_t)n * HID + (k - HID)); }
    } else {
      av = ldg4(P.h1 + lr * HID + k);
      const int n = n0 + lr;
      wv = (n < HID) ? ldg4(P.WA + (size_t)n * (2*HID) + k)
                     : ldg4(P.WB + (size_t)(n - HID) * (2*HID) + k);
    }
    __syncthreads();
    At[lc+0][lr]=av.x; At[lc+1][lr]=av.y; At[lc+2][lr]=av.z; At[lc+3][lr]=av.w;
    Wt[lc+0][lr]=wv.x; Wt[lc+1][lr]=wv.y; Wt[lc+2][lr]=wv.z; Wt[lc+3][lr]=wv.w;
    __syncthreads();
    #pragma unroll
    for (int kk = 0; kk < 32; ++kk) {
      const float2 a = *reinterpret_cast<const float2*>(&At[kk][tm*2]);
      const float2 w = *reinterpret_cast<const float2*>(&Wt[kk][tn*2]);
      a00 += a.x*w.x; a01 += a.x*w.y; a10 += a.y*w.x; a11 += a.y*w.y;
    }
  }
  const int na = n0 + tn*2, ma = tm*2;
  float* dst = P.P + (size_t)sp * BATCH * P.N;
  dst[(size_t)ma     * P.N + na  ] = a00;
  dst[(size_t)ma     * P.N + na+1] = a01;
  dst[(size_t)(ma+1) * P.N + na  ] = a10;
  dst[(size_t)(ma+1) * P.N + na+1] = a11;
}

// reduce 4 K-split partials + combined bias -> LSTM cell update (in-place h,c)
__global__ __launch_bounds__(256) void cellred_k(const float* __restrict__ Pg,
                                                 const float* __restrict__ bsum,
                                                 float* __restrict__ h,
                                                 float* __restrict__ c) {
  const int i = blockIdx.x*256 + threadIdx.x;      // b*HID + n
  const int b = i >> 10, n = i & (HID-1);
  float g[4];
  #pragma unroll
  for (int gi = 0; gi < 4; ++gi) {
    const int jj = gi*HID + n;
    float s = bsum[jj];
    #pragma unroll
    for (int sp = 0; sp < 4; ++sp) s += Pg[((size_t)sp*BATCH + b)*G4 + jj];
    g[gi] = s;
  }
  const float si = 1.f/(1.f+expf(-g[0]));
  const float sf = 1.f/(1.f+expf(-g[1]));
  const float so = 1.f/(1.f+expf(-g[3]));
  const float cn = sf*c[i] + si*tanhf(g[2]);
  c[i] = cn;
  h[i] = so*tanhf(cn);
}

// fused: q-sum, scores, softmax, context (over PreC), attnh finalize -> AH[t]
__global__ __launch_bounds__(256) void attn_k(const float* __restrict__ Pq,
                                              const float* __restrict__ PreAC,
                                              const float* __restrict__ va,
                                              const float* __restrict__ bc,
                                              float* __restrict__ AHt) {
  const int b = blockIdx.x;
  const int tid = threadIdx.x;
  const int lane = tid & 63, wid = tid >> 6;       // 4 waves
  __shared__ float sw[TENC];
  __shared__ float swx[TENC];
  float qreg[16], vreg[16];
  #pragma unroll
  for (int i2 = 0; i2 < 16; ++i2) {
    const int hh = lane + 64*i2;
    qreg[i2] = Pq[(size_t)b*2048 + hh] + Pq[(size_t)(BATCH + b)*2048 + hh];
    vreg[i2] = va[hh];
  }
  for (int t = wid; t < TENC; t += 4) {
    const float* pr = PreAC + ((size_t)t*BATCH + b)*2048;
    float s = 0.f;
    #pragma unroll
    for (int i2 = 0; i2 < 16; ++i2) s += vreg[i2]*tanhf(qreg[i2] + pr[lane + 64*i2]);
    for (int off = 32; off; off >>= 1) s += __shfl_xor(s, off);
    if (lane == 0) sw[t] = s;
  }
  __syncthreads();
  if (wid == 0) {
    const float v = sw[lane];
    float mx = v;
    for (int off = 32; off; off >>= 1) mx = fmaxf(mx, __shfl_xor(mx, off));
    const float e = expf(v - mx);
    float sum = e;
    for (int off = 32; off; off >>= 1) sum += __shfl_xor(sum, off);
    swx[lane] = e / sum;
  }
  __syncthreads();
  for (int hh = tid; hh < HID; hh += 256) {
    float acc = 0.f;
    #pragma unroll 8
    for (int t = 0; t < TENC; ++t)
      acc += swx[t] * PreAC[((size_t)t*BATCH + b)*2048 + HID + hh];
    const float hc = Pq[(size_t)b*2048 + HID + hh]
                   + Pq[(size_t)(BATCH + b)*2048 + HID + hh] + bc[hh];
    AHt[(size_t)b*HID + hh] = tanhf(acc + hc);
  }
}

// ---------- wide GEMM (M-tile 32, N-tile 128, K=1024), 4x4 per thread
// WM 0: logits  C[2016 x 32000] = AH * Wo^T + bo
// WM 1: PreAC   C[2048 x 2048]  = enc * [Wa2; Wc2]^T + [ba; 0]
struct WGP {
  const float* A;       // row stride 1024
  const float* W;       // WM0: Wo (stride 1024); WM1: Wa (stride 2048)
  const float* W2;      // WM1: Wc (stride 2048)
  const float* bias;    // WM0: bo; WM1: ba
  float* C; int ldc;
};

template<int WM>
__global__ __launch_bounds__(256) void wgemm(WGP P) {
  __shared__ float At[32][36];
  __shared__ float Wt[32][132];
  const int j  = threadIdx.x;
  const int n0 = blockIdx.x * 128;
  const int m0 = blockIdx.y * 32;
  const int lr = j >> 3;
  const int lc = (j & 7) << 2;
  const int tn = j & 31;
  const int tm = j >> 5;
  float acc[4][4];
  #pragma unroll
  for (int i=0;i<4;++i) { acc[i][0]=0.f; acc[i][1]=0.f; acc[i][2]=0.f; acc[i][3]=0.f; }
  for (int k0 = 0; k0 < 1024; k0 += 32) {
    const int k = k0 + lc;
    const float4 av = ldg4(P.A + (size_t)(m0+lr)*1024 + k);
    float4 wv[4];
    #pragma unroll
    for (int rep = 0; rep < 4; ++rep) {
      const int n = n0 + lr + rep*32;
      if (WM == 0) wv[rep] = ldg4(P.W + (size_t)n * 1024 + k);
      else wv[rep] = (n < HID) ? ldg4(P.W  + (size_t)n * (2*HID) + HID + k)
                               : ldg4(P.W2 + (size_t)(n-HID) * (2*HID) + HID + k);
    }
    __syncthreads();
    At[lc+0][lr]=av.x; At[lc+1][lr]=av.y; At[lc+2][lr]=av.z; At[lc+3][lr]=av.w;
    #pragma unroll
    for (int rep=0; rep<4; ++rep) {
      const int r = lr + rep*32;
      Wt[lc+0][r]=wv[rep].x; Wt[lc+1][r]=wv[rep].y; Wt[lc+2][r]=wv[rep].z; Wt[lc+3][r]=wv[rep].w;
    }
    __syncthreads();
    #pragma unroll
    for (int kk=0; kk<32; ++kk) {
      const float4 a = *reinterpret_cast<const float4*>(&At[kk][tm*4]);
      const float4 w = *reinterpret_cast<const float4*>(&Wt[kk][tn*4]);
      acc[0][0]+=a.x*w.x; acc[0][1]+=a.x*w.y; acc[0][2]+=a.x*w.z; acc[0][3]+=a.x*w.w;
      acc[1][0]+=a.y*w.x; acc[1][1]+=a.y*w.y; acc[1][2]+=a.y*w.z; acc[1][3]+=a.y*w.w;
      acc[2][0]+=a.z*w.x; acc[2][1]+=a.z*w.y; acc[2][2]+=a.z*w.z; acc[2][3]+=a.z*w.w;
      acc[3][0]+=a.w*w.x; acc[3][1]+=a.w*w.y; acc[3][2]+=a.w*w.z; acc[3][3]+=a.w*w.w;
    }
  }
  const int na = n0 + tn*4, ma = m0 + tm*4;
  float bb[4];
  #pragma unroll
  for (int x=0;x<4;++x) {
    if (WM == 0) bb[x] = P.bias[na+x];
    else         bb[x] = (na < HID) ? P.bias[na+x] : 0.f;
  }
  #pragma unroll
  for (int i=0;i<4;++i) {
    #pragma unroll
    for (int x=0;x<4;++x)
      P.C[(size_t)(ma+i)*P.ldc + na+x] = acc[i][x] + bb[x];
  }
}

// per-(b,t): logits row -> log-softmax in place + argmax word (as float)
__global__ __launch_bounds__(256) void lsm_k(float* __restrict__ out,
                                             float* __restrict__ words) {
  const int b = blockIdx.x;
  const int t = blockIdx.y;
  float* row = out + ((size_t)t*BATCH + b)*VOCAB;
  const int tid = threadIdx.x;
  float m = -INFINITY; int mi = 0;
  for (int v = tid; v < VOCAB; v += 256) {
    const float x = row[v];
    if (x > m) { m = x; mi = v; }
  }
  __shared__ float sm[256]; __shared__ int si[256];
  sm[tid] = m; si[tid] = mi;
  __syncthreads();
  for (int s2 = 128; s2; s2 >>= 1) {
    if (tid < s2) {
      const float om = sm[tid+s2]; const int oi = si[tid+s2];
      if (om > sm[tid] || (om == sm[tid] && oi < si[tid])) { sm[tid]=om; si[tid]=oi; }
    }
    __syncthreads();
  }
  const float mx = sm[0]; const int amax = si[0];
  float s = 0.f;
  for (int v = tid; v < VOCAB; v += 256) s += expf(row[v]-mx);
  __shared__ float ss[256];
  ss[tid] = s; __syncthreads();
  for (int s2=128; s2; s2>>=1) { if (tid < s2) ss[tid] += ss[tid+s2]; __syncthreads(); }
  const float lse = logf(ss[0]) + mx;
  for (int v = tid; v < VOCAB; v += 256) row[v] = row[v] - lse;
  if (tid == 0) words[(size_t)t*BATCH + b] = (float)amax;
}

__global__ __launch_bounds__(256) void init_k(const float* __restrict__ enc_h,
                                              const float* __restrict__ enc_c,
                                              const float* __restrict__ bih0,
                                              const float* __restrict__ bhh0,
                                              const float* __restrict__ bih1,
                                              const float* __restrict__ bhh1,
                                              float* h0, float* h1, float* c0,
                                              float* c1, float* zbuf,
                                              float* bsum0, float* bsum1) {
  const int i = blockIdx.x*256 + threadIdx.x;
  if (i < BATCH*HID) {
    h0[i] = enc_h[i]; h1[i] = enc_h[BATCH*HID + i];
    c0[i] = enc_c[i]; c1[i] = enc_c[BATCH*HID + i];
    zbuf[i] = 0.f;
  }
  if (i < G4) {
    bsum0[i] = bih0[i] + bhh0[i];
    bsum1[i] = bih1[i] + bhh1[i];
  }
}

extern "C" void kernel_launch(void* const* d_in, const int* in_sizes, int n_in,
                              void* d_out, int out_size, void* d_ws, size_t ws_size,
                              hipStream_t stream) {
  const int*   tgt   = (const int*)d_in[0];
  const float* enc_h = (const float*)d_in[1];
  const float* enc_c = (const float*)d_in[2];
  const float* enc   = (const float*)d_in[3];
  const float* emb   = (const float*)d_in[4];
  const float* Wih0  = (const float*)d_in[5];
  const float* Whh0  = (const float*)d_in[6];
  const float* bih0  = (const float*)d_in[7];
  const float* bhh0  = (const float*)d_in[8];
  const float* Wih1  = (const float*)d_in[9];
  const float* Whh1  = (const float*)d_in[10];
  const float* bih1  = (const float*)d_in[11];
  const float* bhh1  = (const float*)d_in[12];
  const float* Wa    = (const float*)d_in[13];
  const float* ba    = (const float*)d_in[14];
  const float* va    = (const float*)d_in[15];
  const float* Wc    = (const float*)d_in[16];
  const float* bc    = (const float*)d_in[17];
  const float* Wo    = (const float*)d_in[18];
  const float* bo    = (const float*)d_in[19];

  float* ws    = (float*)d_ws;
  float* PreAC = ws;                                   // [2048, 2048]
  float* AH    = PreAC + (size_t)2048*2048;            // [63, 32, 1024]
  float* Pg    = AH    + (size_t)NSTEP*BATCH*HID;      // [4, 32, 4096]
  float* Pq    = Pg    + (size_t)4*BATCH*G4;           // [2, 32, 2048]
  float* h0    = Pq    + (size_t)2*BATCH*2048;
  float* c0    = h0  + BATCH*HID;
  float* h1v   = c0  + BATCH*HID;
  float* c1v   = h1v + BATCH*HID;
  float* zbuf  = c1v + BATCH*HID;
  float* bsum0 = zbuf + BATCH*HID;
  float* bsum1 = bsum0 + G4;

  float* out   = (float*)d_out;
  float* words = out + (size_t)NSTEP*BATCH*VOCAB;

  init_k<<<dim3(128), 256, 0, stream>>>(enc_h, enc_c, bih0, bhh0, bih1, bhh1,
                                        h0, h1v, c0, c1v, zbuf, bsum0, bsum1);

  { // PreAC = enc @ [Wa2; Wc2]^T + [ba; 0]  (time-invariant attention terms)
    WGP p; p.A = enc; p.W = Wa; p.W2 = Wc; p.bias = ba; p.C = PreAC; p.ldc = 2048;
    wgemm<1><<<dim3(16, 64), 256, 0, stream>>>(p);
  }

  for (int t = 0; t < NSTEP; ++t) {
    const float* ah_prev = (t == 0) ? zbuf : (AH + (size_t)(t-1)*BATCH*HID);
    { // gates0 partials: [emb|ah|h0] x [Wih0|Whh0], K=2560, 4 splits
      PP p = {}; p.ah = ah_prev; p.h0 = h0; p.emb = emb; p.tgt = tgt; p.t = t;
      p.WA = Wih0; p.WB = Whh0; p.P = Pg; p.N = G4;
      pgemm<0><<<dim3(G4/32, 4), 256, 0, stream>>>(p);
    }
    cellred_k<<<dim3(BATCH*HID/256), 256, 0, stream>>>(Pg, bsum0, h0, c0);
    { // gates1 partials: [h0|h1] x [Wih1|Whh1], K=2048, 4 splits
      PP p = {}; p.h0 = h0; p.h1 = h1v;
      p.WA = Wih1; p.WB = Whh1; p.P = Pg; p.N = G4;
      pgemm<1><<<dim3(G4/32, 4), 256, 0, stream>>>(p);
    }
    cellred_k<<<dim3(BATCH*HID/256), 256, 0, stream>>>(Pg, bsum1, h1v, c1v);
    { // [q | Wc1*h1] partials: h1 x [Wa1; Wc1], K=1024, 2 splits
      PP p = {}; p.h1 = h1v; p.WA = Wa; p.WB = Wc; p.P = Pq; p.N = 2048;
      pgemm<2><<<dim3(2048/32, 2), 256, 0, stream>>>(p);
    }
    // scores+softmax+context(PreC)+attnh -> AH[t]
    attn_k<<<dim3(BATCH), 256, 0, stream>>>(Pq, PreAC, va, bc,
                                            AH + (size_t)t*BATCH*HID);
  }

  { // one batched logits GEMM over all steps: [2016 x 32000], K=1024
    WGP p; p.A = AH; p.W = Wo; p.W2 = nullptr; p.bias = bo; p.C = out; p.ldc = VOCAB;
    wgemm<0><<<dim3(VOCAB/128, (NSTEP*BATCH)/32), 256, 0, stream>>>(p);
  }
  lsm_k<<<dim3(BATCH, NSTEP), 256, 0, stream>>>(out, words);
}